// Round 6
// baseline (287.132 us; speedup 1.0000x reference)
//
#include <hip/hip_runtime.h>
#include <hip/hip_bf16.h>

// ScoreAttention on MI355X (gfx950).
// Pipeline: gn_stats_part+convert_w -> stats_final -> gn_apply -> qkv_gemm
//           -> flash_part(x2 K-split) -> proj_gemm (merge fused in)
// flash v6: 32x32x16 MFMAs, wave = 32 queries x 128 keys, S^T formulation,
// max-free exp2 softmax, P transform C-layout->B-operand via shfl_xor(32)
// + cndmask IN REGISTERS (no LDS, no barrier). proj reads fp32 partials and
// folds softmax 1/l into the B-fragment pack (linearity of GEMM).

typedef __attribute__((ext_vector_type(8))) __bf16 bf16x8;
typedef __attribute__((ext_vector_type(4))) float f32x4;
typedef __attribute__((ext_vector_type(16))) float f32x16;
typedef __attribute__((ext_vector_type(2))) float f32x2;

#define HW 4096
#define C 256
#define NH 8
#define HD 32
#define QSCALE 0.25505654f  /* log2(e)/sqrt(32) */

__device__ inline unsigned short f2bf(float f) {
  union { float f; unsigned int u; } v; v.f = f;
  unsigned int u = v.u;
  return (unsigned short)((u + 0x7fffu + ((u >> 16) & 1u)) >> 16);
}

__device__ inline bf16x8 load8(const unsigned short* p) {
  bf16x8 v;
  __builtin_memcpy(&v, __builtin_assume_aligned(p, 16), 16);
  return v;
}

__device__ inline unsigned int fbits(float f) {
  unsigned int u; __builtin_memcpy(&u, &f, 4); return u;
}

// pack two f32 -> two bf16 in one dword, round-to-nearest-ish (+0x8000)
__device__ inline unsigned int pack_bf2(float lo, float hi) {
  return __builtin_amdgcn_perm(fbits(hi) + 0x8000u, fbits(lo) + 0x8000u, 0x07060302u);
}
// truncating pack (1 instr) — used for P where error budget is generous
__device__ inline unsigned int pack_bf2t(float lo, float hi) {
  return __builtin_amdgcn_perm(fbits(hi), fbits(lo), 0x07060302u);
}

__device__ inline bf16x8 frag4(unsigned a, unsigned b, unsigned c, unsigned d) {
  union { uint4 u; bf16x8 v; } cv;
  cv.u = make_uint4(a, b, c, d);
  return cv.v;
}

// ---------------- GroupNorm partial stats (blocks 0..255) + weight conv (256..511)
__global__ __launch_bounds__(256) void gn_stats_part(const float* __restrict__ x,
                                                     float* __restrict__ parts,
                                                     const float* __restrict__ wq,
                                                     const float* __restrict__ wp,
                                                     unsigned short* __restrict__ wq_b,
                                                     unsigned short* __restrict__ wp_b) {
  if (blockIdx.x >= 256) {
    int base = (blockIdx.x - 256) * 1024 + threadIdx.x * 4;
    #pragma unroll
    for (int k = 0; k < 4; k++) {
      int idx = base + k;
      if (idx < 196608) wq_b[idx] = f2bf(wq[idx]);
      else              wp_b[idx - 196608] = f2bf(wp[idx - 196608]);
    }
    return;
  }
  int i = blockIdx.x;  // 256 blocks, each reduces 8192 contiguous floats
  const float4* p4 = (const float4*)(x + (size_t)i * 8192);
  int t = threadIdx.x;
  float s = 0.f, ss = 0.f;
  for (int k = t; k < 2048; k += 256) {
    float4 v = p4[k];
    s  += v.x + v.y + v.z + v.w;
    ss += v.x*v.x + v.y*v.y + v.z*v.z + v.w*v.w;
  }
  for (int m = 32; m >= 1; m >>= 1) {
    s  += __shfl_down(s, m, 64);
    ss += __shfl_down(ss, m, 64);
  }
  __shared__ float red[8];
  int w = t >> 6;
  if ((t & 63) == 0) { red[w] = s; red[w + 4] = ss; }
  __syncthreads();
  if (t == 0) {
    parts[i]       = red[0] + red[1] + red[2] + red[3];
    parts[256 + i] = red[4] + red[5] + red[6] + red[7];
  }
}

__global__ __launch_bounds__(64) void stats_final(const float* __restrict__ parts,
                                                  float* __restrict__ stats) {
  int t = threadIdx.x;  // 64 (b,group) pairs
  float s  = parts[4*t] + parts[4*t+1] + parts[4*t+2] + parts[4*t+3];
  float ss = parts[256+4*t] + parts[256+4*t+1] + parts[256+4*t+2] + parts[256+4*t+3];
  float mean = s * (1.0f / 32768.0f);
  float var  = ss * (1.0f / 32768.0f) - mean * mean;
  stats[t]      = mean;
  stats[64 + t] = rsqrtf(var + 1e-5f);
}

// ---------------- GroupNorm apply + transpose: x[b][c][s] -> h_t[b][s][c] bf16
__global__ __launch_bounds__(256) void gn_apply(const float* __restrict__ x,
                                                const float* __restrict__ stats,
                                                const float* __restrict__ gamma,
                                                const float* __restrict__ beta,
                                                unsigned short* __restrict__ h_t) {
  __shared__ float tile[64][65];
  int b = blockIdx.z, c0 = blockIdx.y * 64, s0 = blockIdx.x * 64;
  int t = threadIdx.x;
  const float* xb = x + ((size_t)b * C + c0) * HW + s0;
  #pragma unroll
  for (int k = 0; k < 16; k++) {
    int e = k * 256 + t;
    int i = e >> 6, j = e & 63;
    tile[i][j] = xb[(size_t)i * HW + j];
  }
  __syncthreads();
  unsigned short* hb = h_t + ((size_t)b * HW + s0) * C + c0;
  #pragma unroll
  for (int k = 0; k < 16; k++) {
    int e = k * 256 + t;
    int jr = e >> 6, ir = e & 63;
    int c = c0 + ir;
    int g = c >> 3;
    float mean = stats[b * 32 + g];
    float rstd = stats[64 + b * 32 + g];
    float v = (tile[ir][jr] - mean) * rstd * gamma[c] + beta[c];
    hb[(size_t)jr * C + ir] = f2bf(v);
  }
}

// ---------------- QKV GEMM: packed uint2 epilogue stores for q/k
__global__ __launch_bounds__(256) void qkv_gemm(const unsigned short* __restrict__ wq_b,
                                                const unsigned short* __restrict__ h_t,
                                                const float* __restrict__ b_qkv,
                                                unsigned short* __restrict__ q_t,
                                                unsigned short* __restrict__ k_t,
                                                unsigned short* __restrict__ v_t) {
  int lane = threadIdx.x & 63, w = threadIdx.x >> 6;
  int quad = lane >> 4, l16 = lane & 15;
  int m0 = blockIdx.y * 64 + w * 16;
  int n0 = blockIdx.x * 64;
  int b  = blockIdx.z;
  f32x4 acc[4];
  #pragma unroll
  for (int nb = 0; nb < 4; nb++) acc[nb] = (f32x4){0.f, 0.f, 0.f, 0.f};

  const unsigned short* hb = h_t + (size_t)b * HW * C;
  for (int k0 = 0; k0 < 256; k0 += 32) {
    bf16x8 a = load8(wq_b + (size_t)(m0 + l16) * 256 + k0 + quad * 8);
    #pragma unroll
    for (int nb = 0; nb < 4; nb++) {
      int s = n0 + nb * 16 + l16;
      bf16x8 bb = load8(hb + (size_t)s * C + k0 + quad * 8);
      acc[nb] = __builtin_amdgcn_mfma_f32_16x16x32_bf16(a, bb, acc[nb], 0, 0, 0);
    }
  }

  int seg = m0 >> 8;
  int o0 = m0 + quad * 4;             // 4 consecutive output channels
  #pragma unroll
  for (int nb = 0; nb < 4; nb++) {
    int s = n0 + nb * 16 + l16;
    if (seg == 2) {
      #pragma unroll
      for (int r = 0; r < 4; r++)
        v_t[((size_t)b * C + ((o0 + r) - 512)) * HW + s] = f2bf(acc[nb][r] + b_qkv[o0 + r]);
    } else {
      float sc = seg ? 1.0f : QSCALE;
      float v0 = (acc[nb][0] + b_qkv[o0])     * sc;
      float v1 = (acc[nb][1] + b_qkv[o0 + 1]) * sc;
      float v2 = (acc[nb][2] + b_qkv[o0 + 2]) * sc;
      float v3 = (acc[nb][3] + b_qkv[o0 + 3]) * sc;
      int oc = o0 & 255, h = oc >> 5, d = oc & 31;
      unsigned short* dst = seg ? k_t : q_t;
      uint2 dd;
      dd.x = pack_bf2(v0, v1);
      dd.y = pack_bf2(v2, v3);
      *(uint2*)(dst + (((size_t)b * NH + h) * HW + s) * HD + d) = dd;
    }
  }
}

// ---------------- Flash v6: 32x32x16 MFMA, LDS-free P transform via shfl_xor(32)
// grid (32 q-tiles, 16 bh, 2 splits), 4 waves/block, no __shared__ at all
__global__ __launch_bounds__(256) void flash_part(const unsigned short* __restrict__ q_t,
                                                  const unsigned short* __restrict__ k_t,
                                                  const unsigned short* __restrict__ v_t,
                                                  float* __restrict__ po,
                                                  float* __restrict__ pl,
                                                  int jspan) {
  int lane = threadIdx.x & 63, w = threadIdx.x >> 6;
  int n = lane & 31, hi = lane >> 5;
  bool hv = hi != 0;
  int bh = blockIdx.y, b = bh >> 3, h = bh & 7;
  int m0 = blockIdx.x * 128 + w * 32;
  int z = blockIdx.z;

  const unsigned short* Q = q_t + (size_t)bh * HW * HD;
  const unsigned short* K = k_t + (size_t)bh * HW * HD;
  const unsigned short* V = v_t + ((size_t)b * C + h * HD) * HW + (size_t)n * HW;

  // B-operand Q fragments: lane holds query n, k = dhalf*16 + hi*8 + j
  bf16x8 qf0 = load8(Q + (size_t)(m0 + n) * HD + hi * 8);
  bf16x8 qf1 = load8(Q + (size_t)(m0 + n) * HD + 16 + hi * 8);

  f32x2 ps2 = (f32x2){0.f, 0.f};
  f32x16 oT = (f32x16){0.f,0.f,0.f,0.f,0.f,0.f,0.f,0.f,0.f,0.f,0.f,0.f,0.f,0.f,0.f,0.f};
  const f32x16 zero16 = (f32x16){0.f,0.f,0.f,0.f,0.f,0.f,0.f,0.f,0.f,0.f,0.f,0.f,0.f,0.f,0.f,0.f};

  int jbase = z * jspan;
  for (int j0 = jbase; j0 < jbase + jspan; j0 += 128) {
    // K loads (A-operands, needed first)
    bf16x8 kf0[4], kf1[4];
    #pragma unroll
    for (int kb = 0; kb < 4; kb++) {
      const unsigned short* kp = K + (size_t)(j0 + kb * 32 + n) * HD + hi * 8;
      kf0[kb] = load8(kp);
      kf1[kb] = load8(kp + 16);
    }
    // V loads (independent; latency hides under QK + softmax)
    bf16x8 vf[8];
    #pragma unroll
    for (int t = 0; t < 8; t++)
      vf[t] = load8(V + j0 + t * 16 + hi * 8);
    // QK^T
    f32x16 S[4];
    #pragma unroll
    for (int kb = 0; kb < 4; kb++) {
      S[kb] = __builtin_amdgcn_mfma_f32_32x32x16_bf16(kf1[kb], qf1, zero16, 0, 0, 0);
      S[kb] = __builtin_amdgcn_mfma_f32_32x32x16_bf16(kf0[kb], qf0, S[kb], 0, 0, 0);
    }
    // per 32-key block: exp2, psum, pack, shfl-transpose, PV
    #pragma unroll
    for (int kb = 0; kb < 4; kb++) {
      float p[16];
      #pragma unroll
      for (int r = 0; r < 16; r++)
        p[r] = __builtin_amdgcn_exp2f(S[kb][r]);
      f32x2 a0 = (f32x2){p[0] + p[2], p[1] + p[3]};
      f32x2 a1 = (f32x2){p[4] + p[6], p[5] + p[7]};
      f32x2 a2 = (f32x2){p[8] + p[10], p[9] + p[11]};
      f32x2 a3 = (f32x2){p[12] + p[14], p[13] + p[15]};
      ps2 += (a0 + a1) + (a2 + a3);
      // C-layout regs -> packed dwords. Lane (n,hi) holds, per chunk of 16 keys:
      //  lK (regs 0-3):  in-chunk keys 4*hi+{0..3};  hK (regs 4-7): keys 8+4*hi+{0..3}
      unsigned l0 = pack_bf2t(p[0], p[1]),  l1 = pack_bf2t(p[2], p[3]);
      unsigned h0 = pack_bf2t(p[4], p[5]),  h1 = pack_bf2t(p[6], p[7]);
      unsigned l2 = pack_bf2t(p[8], p[9]),  l3 = pack_bf2t(p[10], p[11]);
      unsigned h2 = pack_bf2t(p[12], p[13]), h3 = pack_bf2t(p[14], p[15]);
      // partner's complementary quads
      unsigned rl0 = __shfl_xor(l0, 32, 64), rl1 = __shfl_xor(l1, 32, 64);
      unsigned rh0 = __shfl_xor(h0, 32, 64), rh1 = __shfl_xor(h1, 32, 64);
      unsigned rl2 = __shfl_xor(l2, 32, 64), rl3 = __shfl_xor(l3, 32, 64);
      unsigned rh2 = __shfl_xor(h2, 32, 64), rh3 = __shfl_xor(h3, 32, 64);
      // B-operand fragments: lane (n,hi) needs chunk keys 8*hi + {0..7}
      bf16x8 f0 = frag4(hv ? rh0 : l0, hv ? rh1 : l1, hv ? h0 : rl0, hv ? h1 : rl1);
      bf16x8 f1 = frag4(hv ? rh2 : l2, hv ? rh3 : l3, hv ? h2 : rl2, hv ? h3 : rl3);
      oT = __builtin_amdgcn_mfma_f32_32x32x16_bf16(vf[2 * kb],     f0, oT, 0, 0, 0);
      oT = __builtin_amdgcn_mfma_f32_32x32x16_bf16(vf[2 * kb + 1], f1, oT, 0, 0, 0);
    }
  }

  float psum = ps2.x + ps2.y;
  psum += __shfl_xor(psum, 32, 64);

  // O^T: col=query n, row=d = (reg&3)+8*(reg>>2)+4*hi
  float* pr = po + (((size_t)z * 16 + bh) * HW + (m0 + n)) * 32;
  #pragma unroll
  for (int g = 0; g < 4; g++) {
    f32x4 v4 = (f32x4){oT[4 * g], oT[4 * g + 1], oT[4 * g + 2], oT[4 * g + 3]};
    *(f32x4*)(pr + g * 8 + hi * 4) = v4;
  }
  if (lane < 32)
    pl[((size_t)z * 16 + bh) * HW + m0 + n] = psum;
}

// ---------------- Proj GEMM with fused merge: out = x + Wp*(sum_z PO_z * diag(1/l)) + bp
__global__ __launch_bounds__(256) void proj_gemm(const unsigned short* __restrict__ wp_b,
                                                 const float* __restrict__ po,
                                                 const float* __restrict__ pl,
                                                 const float* __restrict__ b_proj,
                                                 const float* __restrict__ x,
                                                 float* __restrict__ out) {
  int lane = threadIdx.x & 63, w = threadIdx.x >> 6;
  int quad = lane >> 4, l16 = lane & 15;
  int m0 = blockIdx.y * 64 + w * 16;   // o
  int n0 = blockIdx.x * 64;            // s
  int b  = blockIdx.z;
  f32x4 acc[4];
  #pragma unroll
  for (int nb = 0; nb < 4; nb++) acc[nb] = (f32x4){0.f, 0.f, 0.f, 0.f};

  for (int hh = 0; hh < 8; hh++) {
    int bh = b * 8 + hh;
    float inv[4];
    #pragma unroll
    for (int nb = 0; nb < 4; nb++) {
      int s = n0 + nb * 16 + l16;
      float l = pl[(size_t)bh * HW + s] + pl[(size_t)(16 + bh) * HW + s];
      inv[nb] = __builtin_amdgcn_rcpf(l);
    }
    // A: Wp[o][c], c = hh*32 + quad*8 + j
    bf16x8 a = load8(wp_b + (size_t)(m0 + l16) * 256 + hh * 32 + quad * 8);
    #pragma unroll
    for (int z = 0; z < 2; z++) {
      #pragma unroll
      for (int nb = 0; nb < 4; nb++) {
        int s = n0 + nb * 16 + l16;
        const float* pb = po + (((size_t)(z * 16 + bh)) * HW + s) * 32 + quad * 8;
        float4 lo = *(const float4*)pb;
        float4 hi = *(const float4*)(pb + 4);
        unsigned d0 = pack_bf2(lo.x * inv[nb], lo.y * inv[nb]);
        unsigned d1 = pack_bf2(lo.z * inv[nb], lo.w * inv[nb]);
        unsigned d2 = pack_bf2(hi.x * inv[nb], hi.y * inv[nb]);
        unsigned d3 = pack_bf2(hi.z * inv[nb], hi.w * inv[nb]);
        acc[nb] = __builtin_amdgcn_mfma_f32_16x16x32_bf16(a, frag4(d0, d1, d2, d3),
                                                          acc[nb], 0, 0, 0);
      }
    }
  }
  #pragma unroll
  for (int nb = 0; nb < 4; nb++) {
    int s = n0 + nb * 16 + l16;
    #pragma unroll
    for (int r = 0; r < 4; r++) {
      int o = m0 + quad * 4 + r;
      size_t idx = ((size_t)b * C + o) * HW + s;
      out[idx] = acc[nb][r] + b_proj[o] + x[idx];
    }
  }
}

extern "C" void kernel_launch(void* const* d_in, const int* in_sizes, int n_in,
                              void* d_out, int out_size, void* d_ws, size_t ws_size,
                              hipStream_t stream) {
  const float* x      = (const float*)d_in[0];
  const float* w_qkv  = (const float*)d_in[1];
  const float* b_qkv  = (const float*)d_in[2];
  const float* w_proj = (const float*)d_in[3];
  const float* b_proj = (const float*)d_in[4];
  const float* gamma  = (const float*)d_in[5];
  const float* beta   = (const float*)d_in[6];
  float* out = (float*)d_out;

  char* ws = (char*)d_ws;
  float*          stats = (float*)ws;                          // 512 B
  float*          parts = (float*)(ws + 512);                  // 2 KB
  unsigned short* wq_b  = (unsigned short*)(ws + 4096);        // 384 KB
  unsigned short* wp_b  = (unsigned short*)(ws + 397312);      // 128 KB
  unsigned short* h_t   = (unsigned short*)(ws + 528384);      // 4 MB [b][s][c]
  unsigned short* q_t   = (unsigned short*)(ws + 4722688);     // 4 MB [bh][s][d]
  unsigned short* k_t   = (unsigned short*)(ws + 8916992);     // 4 MB [bh][s][d]
  unsigned short* v_t   = (unsigned short*)(ws + 13111296);    // 4 MB [b][c][s]
  float*          po    = (float*)(ws + 17305600);             // 16 MB (2 splits, fp32)
  float*          pl    = (float*)(ws + 34082816);             // 512 KB

  gn_stats_part<<<512, 256, 0, stream>>>(x, parts, w_qkv, w_proj, wq_b, wp_b);
  stats_final<<<1, 64, 0, stream>>>(parts, stats);
  gn_apply<<<dim3(64, 4, 2), 256, 0, stream>>>(x, stats, gamma, beta, h_t);
  qkv_gemm<<<dim3(64, 12, 2), 256, 0, stream>>>(wq_b, h_t, b_qkv, q_t, k_t, v_t);
  flash_part<<<dim3(32, 16, 2), 256, 0, stream>>>(q_t, k_t, v_t, po, pl, HW / 2);
  proj_gemm<<<dim3(64, 4, 2), 256, 0, stream>>>(wp_b, po, pl, b_proj, x, out);
}

// Round 7
// 213.820 us; speedup vs baseline: 1.3429x; 1.3429x over previous
//
#include <hip/hip_runtime.h>
#include <hip/hip_bf16.h>

// ScoreAttention on MI355X (gfx950).
// Pipeline: gn_stats_part+convert_w -> gn_apply(stats folded) -> qkv_gemm
//           -> flash_part(x4 K-split) -> merge_parts -> proj_gemm
// flash v7: 32x32x16 MFMAs, wave = 32 queries x 64 keys/iter, S^T formulation,
// max-free exp2 softmax, LDS P round-trip (18.4KB/block -> 8 blocks/CU),
// K-split=4 for occupancy, bf16 partials.

typedef __attribute__((ext_vector_type(8))) __bf16 bf16x8;
typedef __attribute__((ext_vector_type(4))) float f32x4;
typedef __attribute__((ext_vector_type(16))) float f32x16;

#define HW 4096
#define C 256
#define NH 8
#define HD 32
#define QSCALE 0.25505654f  /* log2(e)/sqrt(32) */
#define PST 72              /* shorts per P row (64 keys + 8 pad), 16B-aligned rows */

__device__ inline unsigned short f2bf(float f) {
  union { float f; unsigned int u; } v; v.f = f;
  unsigned int u = v.u;
  return (unsigned short)((u + 0x7fffu + ((u >> 16) & 1u)) >> 16);
}

__device__ inline bf16x8 load8(const unsigned short* p) {
  bf16x8 v;
  __builtin_memcpy(&v, __builtin_assume_aligned(p, 16), 16);
  return v;
}

__device__ inline unsigned int fbits(float f) {
  unsigned int u; __builtin_memcpy(&u, &f, 4); return u;
}
__device__ inline float bits2f(unsigned int u) {
  float f; __builtin_memcpy(&f, &u, 4); return f;
}

// pack two f32 -> two bf16 in one dword (round via +0x8000)
__device__ inline unsigned int pack_bf2(float lo, float hi) {
  return __builtin_amdgcn_perm(fbits(hi) + 0x8000u, fbits(lo) + 0x8000u, 0x07060302u);
}
// truncating pack (1 instr) — for P, where the error budget is generous
__device__ inline unsigned int pack_bf2t(float lo, float hi) {
  return __builtin_amdgcn_perm(fbits(hi), fbits(lo), 0x07060302u);
}

// ---------------- GroupNorm partial stats (blocks 0..255) + weight conv (256..511)
__global__ __launch_bounds__(256) void gn_stats_part(const float* __restrict__ x,
                                                     float* __restrict__ parts,
                                                     const float* __restrict__ wq,
                                                     const float* __restrict__ wp,
                                                     unsigned short* __restrict__ wq_b,
                                                     unsigned short* __restrict__ wp_b) {
  if (blockIdx.x >= 256) {
    int base = (blockIdx.x - 256) * 1024 + threadIdx.x * 4;
    #pragma unroll
    for (int k = 0; k < 4; k++) {
      int idx = base + k;
      if (idx < 196608) wq_b[idx] = f2bf(wq[idx]);
      else              wp_b[idx - 196608] = f2bf(wp[idx - 196608]);
    }
    return;
  }
  int i = blockIdx.x;  // 256 blocks, each reduces 8192 contiguous floats
  const float4* p4 = (const float4*)(x + (size_t)i * 8192);
  int t = threadIdx.x;
  float s = 0.f, ss = 0.f;
  for (int k = t; k < 2048; k += 256) {
    float4 v = p4[k];
    s  += v.x + v.y + v.z + v.w;
    ss += v.x*v.x + v.y*v.y + v.z*v.z + v.w*v.w;
  }
  for (int m = 32; m >= 1; m >>= 1) {
    s  += __shfl_down(s, m, 64);
    ss += __shfl_down(ss, m, 64);
  }
  __shared__ float red[8];
  int w = t >> 6;
  if ((t & 63) == 0) { red[w] = s; red[w + 4] = ss; }
  __syncthreads();
  if (t == 0) {
    parts[i]       = red[0] + red[1] + red[2] + red[3];
    parts[256 + i] = red[4] + red[5] + red[6] + red[7];
  }
}

// ---------------- GroupNorm apply + transpose (finalizes stats from parts)
__global__ __launch_bounds__(256) void gn_apply(const float* __restrict__ x,
                                                const float* __restrict__ parts,
                                                const float* __restrict__ gamma,
                                                const float* __restrict__ beta,
                                                unsigned short* __restrict__ h_t) {
  __shared__ float tile[64][65];
  __shared__ float gmean[8], grstd[8];
  int b = blockIdx.z, c0 = blockIdx.y * 64, s0 = blockIdx.x * 64;
  int t = threadIdx.x;
  if (t < 8) {
    int bg = b * 32 + (c0 >> 3) + t;
    float s  = (parts[4*bg] + parts[4*bg+1]) + (parts[4*bg+2] + parts[4*bg+3]);
    float ss = (parts[256+4*bg] + parts[256+4*bg+1]) + (parts[256+4*bg+2] + parts[256+4*bg+3]);
    float mean = s * (1.0f / 32768.0f);
    float var  = ss * (1.0f / 32768.0f) - mean * mean;
    gmean[t] = mean;
    grstd[t] = rsqrtf(var + 1e-5f);
  }
  const float* xb = x + ((size_t)b * C + c0) * HW + s0;
  #pragma unroll
  for (int k = 0; k < 16; k++) {
    int e = k * 256 + t;
    int i = e >> 6, j = e & 63;
    tile[i][j] = xb[(size_t)i * HW + j];
  }
  __syncthreads();
  unsigned short* hb = h_t + ((size_t)b * HW + s0) * C + c0;
  #pragma unroll
  for (int k = 0; k < 16; k++) {
    int e = k * 256 + t;
    int jr = e >> 6, ir = e & 63;
    int c = c0 + ir, gl = ir >> 3;
    float v = (tile[ir][jr] - gmean[gl]) * grstd[gl] * gamma[c] + beta[c];
    hb[(size_t)jr * C + ir] = f2bf(v);
  }
}

// ---------------- QKV GEMM: packed uint2 epilogue stores for q/k
__global__ __launch_bounds__(256) void qkv_gemm(const unsigned short* __restrict__ wq_b,
                                                const unsigned short* __restrict__ h_t,
                                                const float* __restrict__ b_qkv,
                                                unsigned short* __restrict__ q_t,
                                                unsigned short* __restrict__ k_t,
                                                unsigned short* __restrict__ v_t) {
  int lane = threadIdx.x & 63, w = threadIdx.x >> 6;
  int quad = lane >> 4, l16 = lane & 15;
  int m0 = blockIdx.y * 64 + w * 16;
  int n0 = blockIdx.x * 64;
  int b  = blockIdx.z;
  f32x4 acc[4];
  #pragma unroll
  for (int nb = 0; nb < 4; nb++) acc[nb] = (f32x4){0.f, 0.f, 0.f, 0.f};

  const unsigned short* hb = h_t + (size_t)b * HW * C;
  for (int k0 = 0; k0 < 256; k0 += 32) {
    bf16x8 a = load8(wq_b + (size_t)(m0 + l16) * 256 + k0 + quad * 8);
    #pragma unroll
    for (int nb = 0; nb < 4; nb++) {
      int s = n0 + nb * 16 + l16;
      bf16x8 bb = load8(hb + (size_t)s * C + k0 + quad * 8);
      acc[nb] = __builtin_amdgcn_mfma_f32_16x16x32_bf16(a, bb, acc[nb], 0, 0, 0);
    }
  }

  int seg = m0 >> 8;
  int o0 = m0 + quad * 4;
  #pragma unroll
  for (int nb = 0; nb < 4; nb++) {
    int s = n0 + nb * 16 + l16;
    if (seg == 2) {
      #pragma unroll
      for (int r = 0; r < 4; r++)
        v_t[((size_t)b * C + ((o0 + r) - 512)) * HW + s] = f2bf(acc[nb][r] + b_qkv[o0 + r]);
    } else {
      float sc = seg ? 1.0f : QSCALE;
      float v0 = (acc[nb][0] + b_qkv[o0])     * sc;
      float v1 = (acc[nb][1] + b_qkv[o0 + 1]) * sc;
      float v2 = (acc[nb][2] + b_qkv[o0 + 2]) * sc;
      float v3 = (acc[nb][3] + b_qkv[o0 + 3]) * sc;
      int oc = o0 & 255, h = oc >> 5, d = oc & 31;
      unsigned short* dst = seg ? k_t : q_t;
      uint2 dd;
      dd.x = pack_bf2(v0, v1);
      dd.y = pack_bf2(v2, v3);
      *(uint2*)(dst + (((size_t)b * NH + h) * HW + s) * HD + d) = dd;
    }
  }
}

// ---------------- Flash v7: 32x32x16 MFMA, 64-key chunks, K-split=4
// grid (32 q-tiles, 16 bh, 4 splits), 4 waves/block, LDS 18.4KB
__global__ __launch_bounds__(256) void flash_part(const unsigned short* __restrict__ q_t,
                                                  const unsigned short* __restrict__ k_t,
                                                  const unsigned short* __restrict__ v_t,
                                                  unsigned short* __restrict__ po,
                                                  float* __restrict__ pl,
                                                  int jspan) {
  int lane = threadIdx.x & 63, w = threadIdx.x >> 6;
  int n = lane & 31, hi = lane >> 5;
  int bh = blockIdx.y, b = bh >> 3, h = bh & 7;
  int m0 = blockIdx.x * 128 + w * 32;
  int z = blockIdx.z;

  __shared__ __align__(16) unsigned short pbuf[4][32 * PST];
  unsigned short* prow = &pbuf[w][0] + n * PST;

  const unsigned short* Q = q_t + (size_t)bh * HW * HD;
  const unsigned short* K = k_t + (size_t)bh * HW * HD;
  const unsigned short* V = v_t + ((size_t)b * C + h * HD) * HW + (size_t)n * HW;

  // B-operand Q fragments: lane holds query n, k = dhalf*16 + hi*8 + j
  bf16x8 qf0 = load8(Q + (size_t)(m0 + n) * HD + hi * 8);
  bf16x8 qf1 = load8(Q + (size_t)(m0 + n) * HD + 16 + hi * 8);

  float psum = 0.f;
  f32x16 oT = (f32x16){0.f,0.f,0.f,0.f,0.f,0.f,0.f,0.f,0.f,0.f,0.f,0.f,0.f,0.f,0.f,0.f};
  const f32x16 zero16 = (f32x16){0.f,0.f,0.f,0.f,0.f,0.f,0.f,0.f,0.f,0.f,0.f,0.f,0.f,0.f,0.f,0.f};

  int jbase = z * jspan;
  for (int j0 = jbase; j0 < jbase + jspan; j0 += 64) {
    // K loads (A-operands)
    bf16x8 kf0[2], kf1[2];
    #pragma unroll
    for (int kb = 0; kb < 2; kb++) {
      const unsigned short* kp = K + (size_t)(j0 + kb * 32 + n) * HD + hi * 8;
      kf0[kb] = load8(kp);
      kf1[kb] = load8(kp + 16);
    }
    // V loads (independent)
    bf16x8 vf[4];
    #pragma unroll
    for (int t = 0; t < 4; t++)
      vf[t] = load8(V + j0 + t * 16 + hi * 8);
    // QK^T
    f32x16 S[2];
    #pragma unroll
    for (int kb = 0; kb < 2; kb++) {
      S[kb] = __builtin_amdgcn_mfma_f32_32x32x16_bf16(kf1[kb], qf1, zero16, 0, 0, 0);
      S[kb] = __builtin_amdgcn_mfma_f32_32x32x16_bf16(kf0[kb], qf0, S[kb], 0, 0, 0);
    }
    // exp2 / sum / pack / LDS write
    #pragma unroll
    for (int kb = 0; kb < 2; kb++) {
      float p[16];
      #pragma unroll
      for (int r = 0; r < 16; r++)
        p[r] = __builtin_amdgcn_exp2f(S[kb][r]);
      float s0 = (p[0] + p[1]) + (p[2] + p[3]);
      float s1 = (p[4] + p[5]) + (p[6] + p[7]);
      float s2 = (p[8] + p[9]) + (p[10] + p[11]);
      float s3 = (p[12] + p[13]) + (p[14] + p[15]);
      psum += (s0 + s1) + (s2 + s3);
      #pragma unroll
      for (int g = 0; g < 4; g++) {
        uint2 dd;
        dd.x = pack_bf2t(p[4 * g], p[4 * g + 1]);
        dd.y = pack_bf2t(p[4 * g + 2], p[4 * g + 3]);
        // P[query n][key kb*32 + g*8 + 4*hi + {0..3}]
        *(uint2*)(prow + kb * 32 + g * 8 + hi * 4) = dd;
      }
    }
    // PV: O^T[d][q] += V^T[d][k] * P^T[k][q]
    #pragma unroll
    for (int t = 0; t < 4; t++) {
      bf16x8 pf = load8(prow + t * 16 + hi * 8);   // B: n=query, k=keys
      oT = __builtin_amdgcn_mfma_f32_32x32x16_bf16(vf[t], pf, oT, 0, 0, 0);
    }
  }

  psum += __shfl_xor(psum, 32, 64);

  // O^T partials (bf16): col=query n, row d = (reg&3)+8*(reg>>2)+4*hi
  unsigned short* pr = po + (((size_t)z * 16 + bh) * HW + (m0 + n)) * 32;
  #pragma unroll
  for (int g = 0; g < 4; g++) {
    uint2 dd;
    dd.x = pack_bf2(oT[4 * g], oT[4 * g + 1]);
    dd.y = pack_bf2(oT[4 * g + 2], oT[4 * g + 3]);
    *(uint2*)(pr + g * 8 + hi * 4) = dd;
  }
  if (lane < 32)
    pl[((size_t)z * 16 + bh) * HW + m0 + n] = psum;
}

// ---------------- merge 4 partials -> ao_t[b][s][c] bf16
__global__ __launch_bounds__(256) void merge_parts(const unsigned short* __restrict__ po,
                                                   const float* __restrict__ pl,
                                                   unsigned short* __restrict__ ao_t) {
  int g = blockIdx.x * 256 + threadIdx.x;   // [0, 16*4096*4): one 8-d chunk each
  int q4 = g & 3, s = (g >> 2) & 4095, bh = g >> 14;
  const uint4* p4 = (const uint4*)po;
  size_t idx = ((size_t)bh * HW + s) * 4 + q4;
  const size_t zstride = (size_t)16 * HW * 4;
  float acc[8] = {0,0,0,0,0,0,0,0};
  float l = 0.f;
  #pragma unroll
  for (int z = 0; z < 4; z++) {
    uint4 v = p4[z * zstride + idx];
    acc[0] += bits2f(v.x << 16);  acc[1] += bits2f(v.x & 0xffff0000u);
    acc[2] += bits2f(v.y << 16);  acc[3] += bits2f(v.y & 0xffff0000u);
    acc[4] += bits2f(v.z << 16);  acc[5] += bits2f(v.z & 0xffff0000u);
    acc[6] += bits2f(v.w << 16);  acc[7] += bits2f(v.w & 0xffff0000u);
    l += pl[((size_t)z * 16 + bh) * HW + s];
  }
  float inv = 1.0f / l;
  int b = bh >> 3, h = bh & 7;
  uint4 o;
  o.x = pack_bf2(acc[0] * inv, acc[1] * inv);
  o.y = pack_bf2(acc[2] * inv, acc[3] * inv);
  o.z = pack_bf2(acc[4] * inv, acc[5] * inv);
  o.w = pack_bf2(acc[6] * inv, acc[7] * inv);
  *(uint4*)(ao_t + ((size_t)b * HW + s) * C + h * HD + q4 * 8) = o;
}

// ---------------- Proj GEMM + bias + residual
__global__ __launch_bounds__(256) void proj_gemm(const unsigned short* __restrict__ wp_b,
                                                 const unsigned short* __restrict__ ao_t,
                                                 const float* __restrict__ b_proj,
                                                 const float* __restrict__ x,
                                                 float* __restrict__ out) {
  int lane = threadIdx.x & 63, w = threadIdx.x >> 6;
  int quad = lane >> 4, l16 = lane & 15;
  int m0 = blockIdx.y * 64 + w * 16;
  int n0 = blockIdx.x * 64;
  int b  = blockIdx.z;
  f32x4 acc[4];
  #pragma unroll
  for (int nb = 0; nb < 4; nb++) acc[nb] = (f32x4){0.f, 0.f, 0.f, 0.f};

  const unsigned short* ab = ao_t + (size_t)b * HW * C;
  for (int k0 = 0; k0 < 256; k0 += 32) {
    bf16x8 a = load8(wp_b + (size_t)(m0 + l16) * 256 + k0 + quad * 8);
    #pragma unroll
    for (int nb = 0; nb < 4; nb++) {
      int s = n0 + nb * 16 + l16;
      bf16x8 bb = load8(ab + (size_t)s * C + k0 + quad * 8);
      acc[nb] = __builtin_amdgcn_mfma_f32_16x16x32_bf16(a, bb, acc[nb], 0, 0, 0);
    }
  }
  #pragma unroll
  for (int nb = 0; nb < 4; nb++) {
    int s = n0 + nb * 16 + l16;
    #pragma unroll
    for (int r = 0; r < 4; r++) {
      int o = m0 + quad * 4 + r;
      size_t idx = ((size_t)b * C + o) * HW + s;
      out[idx] = acc[nb][r] + b_proj[o] + x[idx];
    }
  }
}

extern "C" void kernel_launch(void* const* d_in, const int* in_sizes, int n_in,
                              void* d_out, int out_size, void* d_ws, size_t ws_size,
                              hipStream_t stream) {
  const float* x      = (const float*)d_in[0];
  const float* w_qkv  = (const float*)d_in[1];
  const float* b_qkv  = (const float*)d_in[2];
  const float* w_proj = (const float*)d_in[3];
  const float* b_proj = (const float*)d_in[4];
  const float* gamma  = (const float*)d_in[5];
  const float* beta   = (const float*)d_in[6];
  float* out = (float*)d_out;

  char* ws = (char*)d_ws;
  float*          parts = (float*)ws;                          // 2 KB
  unsigned short* wq_b  = (unsigned short*)(ws + 4096);        // 384 KB
  unsigned short* wp_b  = (unsigned short*)(ws + 397312);      // 128 KB
  unsigned short* h_t   = (unsigned short*)(ws + 528384);      // 4 MB [b][s][c]; reused as ao_t
  unsigned short* q_t   = (unsigned short*)(ws + 4722688);     // 4 MB [bh][s][d]
  unsigned short* k_t   = (unsigned short*)(ws + 8916992);     // 4 MB [bh][s][d]
  unsigned short* v_t   = (unsigned short*)(ws + 13111296);    // 4 MB [b][c][s]
  unsigned short* po    = (unsigned short*)(ws + 17305600);    // 16 MB (4 splits, bf16)
  float*          pl    = (float*)(ws + 34082816);             // 1 MB
  unsigned short* ao_t  = h_t;  // h_t dead after qkv_gemm

  gn_stats_part<<<512, 256, 0, stream>>>(x, parts, w_qkv, w_proj, wq_b, wp_b);
  gn_apply<<<dim3(64, 4, 2), 256, 0, stream>>>(x, parts, gamma, beta, h_t);
  qkv_gemm<<<dim3(64, 12, 2), 256, 0, stream>>>(wq_b, h_t, b_qkv, q_t, k_t, v_t);
  flash_part<<<dim3(32, 16, 4), 256, 0, stream>>>(q_t, k_t, v_t, po, pl, HW / 4);
  merge_parts<<<1024, 256, 0, stream>>>(po, pl, ao_t);
  proj_gemm<<<dim3(64, 4, 2), 256, 0, stream>>>(wp_b, ao_t, b_proj, x, out);
}